// Round 6
// baseline (478.970 us; speedup 1.0000x reference)
//
#include <hip/hip_runtime.h>
#include <limits.h>

#define D 128
#define NBK 768          // adjacency buckets: key>>15, max key 25M-1 -> 762

typedef __attribute__((ext_vector_type(8))) short bf16x8;
typedef __attribute__((ext_vector_type(4))) float f32x4;

static __device__ __forceinline__ unsigned short f2bf(float f) {
    unsigned u = __builtin_bit_cast(unsigned, f);
    u += 0x7FFFu + ((u >> 16) & 1u);            // RNE
    return (unsigned short)(u >> 16);
}
static __device__ __forceinline__ float bf2f(unsigned u16) {
    unsigned u = u16 << 16;
    return __builtin_bit_cast(float, u);
}
static __device__ __forceinline__ bf16x8 load_frag(const unsigned short* p) {
    uint4 v = *(const uint4*)p;
    return __builtin_bit_cast(bf16x8, v);
}
static __device__ __forceinline__ void acc8(float* a, uint4 v) {
    a[0] += bf2f(v.x & 0xffff); a[1] += bf2f(v.x >> 16);
    a[2] += bf2f(v.y & 0xffff); a[3] += bf2f(v.y >> 16);
    a[4] += bf2f(v.z & 0xffff); a[5] += bf2f(v.z >> 16);
    a[6] += bf2f(v.w & 0xffff); a[7] += bf2f(v.w >> 16);
}
static __device__ __forceinline__ ushort4 pack4(const float* a, float s) {
    ushort4 o;
    o.x = f2bf(a[0] * s); o.y = f2bf(a[1] * s);
    o.z = f2bf(a[2] * s); o.w = f2bf(a[3] * s);
    return o;
}

// ---------------- zero-fill scratch counters ----------------
__global__ __launch_bounds__(256) void zero_k(float4* __restrict__ b, size_t nb)
{
    size_t i = (size_t)blockIdx.x * 256 + threadIdx.x;
    if (i < nb) b[i] = make_float4(0.f, 0.f, 0.f, 0.f);
}

// ---------------- embed table -> bf16 ----------------
__global__ __launch_bounds__(256) void epack_k(
    const float* __restrict__ embed, unsigned short* __restrict__ e16, int n4)
{
    int i = blockIdx.x * 256 + threadIdx.x;
    if (i >= n4) return;
    float4 v = *(const float4*)&embed[(size_t)i * 4];
    ushort4 o;
    o.x = f2bf(v.x); o.y = f2bf(v.y); o.z = f2bf(v.z); o.w = f2bf(v.w);
    *(ushort4*)&e16[(size_t)i * 4] = o;
}

// ---------------- embedding masked mean-pool: 16 nodes/block, 16 lanes x 16B ----------------
__global__ __launch_bounds__(256) void embed_pool_k(
    const int* __restrict__ x, const unsigned short* __restrict__ e16,
    unsigned short* __restrict__ h16, int n, int L)
{
    __shared__ int toks[16][32];   // L <= 32
    int t = threadIdx.x;
    int sub = t >> 4, s = t & 15;
    int node = blockIdx.x * 16 + sub;
    for (int j = t; j < 16 * L; j += 256) {
        int nd = blockIdx.x * 16 + j / L;
        toks[j / L][j % L] = (nd < n) ? x[(size_t)nd * L + (j % L)] : 0;
    }
    __syncthreads();
    if (node >= n) return;
    float acc[8] = {};
    int cnt = 0;
    for (int l = 0; l < L; ++l) {
        int tok = toks[sub][l];
        if (tok != 0) {
            acc8(acc, *(const uint4*)&e16[(size_t)tok * D + s * 8]);
            cnt++;
        }
    }
    float inv = 1.0f / (float)(cnt > 0 ? cnt : 1);
    ushort4 lo = pack4(acc, inv), hi = pack4(acc + 4, inv);
    *(ushort4*)&h16[(size_t)node * D + s * 8]     = lo;
    *(ushort4*)&h16[(size_t)node * D + s * 8 + 4] = hi;
}

// ---------------- pack W into MFMA B-fragment order (bf16) ----------------
__global__ __launch_bounds__(256) void wpack_k(
    const float* __restrict__ Wl, const float* __restrict__ Wr,
    unsigned short* __restrict__ Wp, int NL)
{
    int idx = blockIdx.x * 256 + threadIdx.x;
    if (idx >= NL * 2 * 16384) return;
    int m = idx >> 14;
    int r = idx & 16383;
    int j = r & 7;
    int lane = (r >> 3) & 63;
    int cb = (r >> 9) & 7;
    int kb = (r >> 12) & 3;
    const float* W = ((m & 1) ? Wr : Wl) + (size_t)(m >> 1) * D * D;
    int k = kb * 32 + (lane >> 4) * 8 + j;
    int c = cb * 16 + (lane & 15);
    Wp[idx] = f2bf(W[(size_t)k * D + c]);
}

// ---------------- degree count + adjacency-bucket histogram ----------------
// degall = [deg(N) | bcnt(NBK)]. 8192 edges/block; LDS bucket histogram.
__global__ __launch_bounds__(256) void deghist_k(
    const int* __restrict__ ei, const int* __restrict__ pool,
    int* __restrict__ degall, int E, int n, int P)
{
    __shared__ int hist[NBK];
    int t = threadIdx.x;
    for (int i = t; i < NBK; i += 256) hist[i] = 0;
    __syncthreads();
    int base = blockIdx.x * 8192;
    for (int i = 0; i < 32; ++i) {
        int e = base + i * 256 + t;
        if (e >= E) break;
        int src = ei[e], dst = ei[E + e];
        atomicAdd(&degall[dst], 1);
        int sp = pool[src], dp = pool[dst];
        if (sp != dp) atomicAdd(&hist[(sp * P + dp) >> 15], 1);
    }
    __syncthreads();
    for (int i = t; i < NBK; i += 256) {
        int v = hist[i];
        if (v) atomicAdd(&degall[n + i], v);
    }
}

// ---------------- hierarchical exclusive scan of degall -> rpall ----------------
__global__ __launch_bounds__(256) void scan_partial_k(
    const int* __restrict__ deg, int* __restrict__ bsum, int n)
{
    int b = blockIdx.x, t = threadIdx.x;
    int i0 = b * 1024 + t * 4;
    int s = 0;
    #pragma unroll
    for (int k = 0; k < 4; ++k) { int i = i0 + k; if (i < n) s += deg[i]; }
    for (int off = 32; off > 0; off >>= 1) s += __shfl_down(s, off, 64);
    __shared__ int sm4[4];
    if ((t & 63) == 0) sm4[t >> 6] = s;
    __syncthreads();
    if (t == 0) bsum[b] = sm4[0] + sm4[1] + sm4[2] + sm4[3];
}

__global__ __launch_bounds__(256) void scan_bsum_k(
    const int* __restrict__ bsum, int* __restrict__ boff, int nb)
{
    __shared__ int sm[256];
    int t = threadIdx.x;
    sm[t] = (t < nb) ? bsum[t] : 0;
    __syncthreads();
    for (int off = 1; off < 256; off <<= 1) {
        int add = (t >= off) ? sm[t - off] : 0;
        __syncthreads();
        sm[t] += add;
        __syncthreads();
    }
    if (t < nb) boff[t] = (t > 0) ? sm[t - 1] : 0;
}

__global__ __launch_bounds__(256) void scan_final_k(
    const int* __restrict__ deg, const int* __restrict__ boff,
    int* __restrict__ rp, int n)
{
    __shared__ int sm[256];
    int b = blockIdx.x, t = threadIdx.x;
    int i0 = b * 1024 + t * 4;
    int v[4];
    #pragma unroll
    for (int k = 0; k < 4; ++k) { int i = i0 + k; v[k] = (i < n) ? deg[i] : 0; }
    v[1] += v[0]; v[2] += v[1]; v[3] += v[2];
    sm[t] = v[3];
    __syncthreads();
    for (int off = 1; off < 256; off <<= 1) {
        int add = (t >= off) ? sm[t - off] : 0;
        __syncthreads();
        sm[t] += add;
        __syncthreads();
    }
    int base = boff[b] + ((t > 0) ? sm[t - 1] : 0);
    if (b == 0 && t == 0) rp[0] = 0;
    #pragma unroll
    for (int k = 0; k < 4; ++k) {
        int i = i0 + k;
        if (i < n) rp[i + 1] = base + v[k];
    }
}

// ---------------- edge pass 2: CSR scatter + bucket key scatter ----------------
__global__ __launch_bounds__(256) void edge_pass2_k(
    const int* __restrict__ ei, const int* __restrict__ rpall,
    const int* __restrict__ pool, int* __restrict__ cur, int* __restrict__ bcur,
    int* __restrict__ col, int* __restrict__ kbuf, int E, int n, int P)
{
    int e = blockIdx.x * 256 + threadIdx.x;
    if (e >= E) return;
    int src = ei[e], dst = ei[E + e];
    int pos = atomicAdd(&cur[dst], 1);
    col[rpall[dst] + pos] = src;
    int sp = pool[src], dp = pool[dst];
    if (sp != dp) {
        int key = sp * P + dp;
        int b = key >> 15;
        int kpos = atomicAdd(&bcur[b], 1);
        kbuf[(rpall[n + b] - E) + kpos] = key;
    }
}

// ---------------- adjacency write: one block per bucket (128KB region) ----------------
__global__ __launch_bounds__(256) void adj_write_k(
    const int* __restrict__ rpall, const int* __restrict__ kbuf,
    float* __restrict__ adj, int E, int n)
{
    int b = blockIdx.x;
    int s = rpall[n + b] - E;
    int e = rpall[n + b + 1] - E;
    for (int i = s + threadIdx.x; i < e; i += 256)
        adj[(size_t)kbuf[i]] = 1.0f;
}

// ---------------- neighbor mean-aggregate: quarter-wave per edge, 8 edges in flight ----------------
__global__ __launch_bounds__(256) void aggregate_k(
    const unsigned short* __restrict__ h16, const int* __restrict__ rp,
    const int* __restrict__ col, unsigned short* __restrict__ agg16, int n)
{
    int node = blockIdx.x * 4 + (threadIdx.x >> 6);
    int lane = threadIdx.x & 63;
    if (node >= n) return;
    int beg = rp[node], end = rp[node + 1];
    int q = lane >> 4, s = lane & 15;
    float acc[8] = {};
    int e = beg + q;
    for (; e + 4 < end; e += 8) {
        int s0 = col[e], s1 = col[e + 4];
        uint4 v0 = *(const uint4*)&h16[(size_t)s0 * D + s * 8];
        uint4 v1 = *(const uint4*)&h16[(size_t)s1 * D + s * 8];
        acc8(acc, v0);
        acc8(acc, v1);
    }
    if (e < end)
        acc8(acc, *(const uint4*)&h16[(size_t)col[e] * D + s * 8]);
    #pragma unroll
    for (int k = 0; k < 8; ++k) {
        acc[k] += __shfl_xor(acc[k], 16, 64);
        acc[k] += __shfl_xor(acc[k], 32, 64);
    }
    if (q == 0) {
        int dg = end - beg;
        float inv = 1.0f / (float)(dg > 0 ? dg : 1);
        ushort4 lo = pack4(acc, inv), hi = pack4(acc + 4, inv);
        *(ushort4*)&agg16[(size_t)node * D + s * 8]     = lo;
        *(ushort4*)&agg16[(size_t)node * D + s * 8 + 4] = hi;
    }
}

// ---------------- SAGE layer GEMM via MFMA (in-place safe) ----------------
__global__ __launch_bounds__(256) void sage_gemm_mfma_k(
    const unsigned short* __restrict__ agg16, unsigned short* __restrict__ h16,
    const unsigned short* __restrict__ Wp,   // [2][4][8][64][8]
    const float* __restrict__ bias, int n)
{
    int t = threadIdx.x;
    int w = t >> 6, lane = t & 63;
    int node0 = blockIdx.x * 128 + w * 32;
    int row = lane & 15, g = lane >> 4;

    f32x4 acc[2][8];
    #pragma unroll
    for (int i = 0; i < 2; ++i)
        #pragma unroll
        for (int c = 0; c < 8; ++c)
            acc[i][c] = (f32x4){0.f, 0.f, 0.f, 0.f};

    float bs[8];
    #pragma unroll
    for (int cb = 0; cb < 8; ++cb) bs[cb] = bias[cb * 16 + row];

    bool ok0 = (node0 < n);
    bool ok1 = (node0 + 16 < n);

    #pragma unroll
    for (int kb = 0; kb < 8; ++kb) {
        const unsigned short* Asrc = (kb < 4) ? agg16 : h16;
        int ko = (kb & 3) * 32 + g * 8;
        bf16x8 a0 = (bf16x8){0,0,0,0,0,0,0,0};
        bf16x8 a1 = a0;
        if (ok0) a0 = load_frag(&Asrc[(size_t)(node0 + row) * D + ko]);
        if (ok1) a1 = load_frag(&Asrc[(size_t)(node0 + 16 + row) * D + ko]);
        const unsigned short* wp = Wp + ((kb < 4) ? 0 : 16384) + (size_t)(kb & 3) * 4096;
        #pragma unroll
        for (int cb = 0; cb < 8; ++cb) {
            bf16x8 b = load_frag(&wp[(cb * 64 + lane) * 8]);
            acc[0][cb] = __builtin_amdgcn_mfma_f32_16x16x32_bf16(a0, b, acc[0][cb], 0, 0, 0);
            acc[1][cb] = __builtin_amdgcn_mfma_f32_16x16x32_bf16(a1, b, acc[1][cb], 0, 0, 0);
        }
    }

    #pragma unroll
    for (int rg = 0; rg < 2; ++rg) {
        int nb = node0 + rg * 16;
        if (nb >= n) break;
        #pragma unroll
        for (int cb = 0; cb < 8; ++cb) {
            int c = cb * 16 + row;
            #pragma unroll
            for (int j = 0; j < 4; ++j) {
                int node = nb + g * 4 + j;
                float v = fmaxf(acc[rg][cb][j] + bs[cb], 0.f);
                h16[(size_t)node * D + c] = f2bf(v);
            }
        }
    }
}

// ---------------- pooled mean + batch max (pool_idx sorted/grouped; no atomics) ----------------
__global__ __launch_bounds__(128) void poolmean_k(
    const unsigned short* __restrict__ h16, const int* __restrict__ pool,
    const int* __restrict__ nbatch, float* __restrict__ outx,
    float* __restrict__ outb, int n, int P)
{
    int p = blockIdx.x;
    int d = threadIdx.x;
    int lo = 0, hi = n;
    while (lo < hi) { int mid = (lo + hi) >> 1; if (pool[mid] < p) lo = mid + 1; else hi = mid; }
    int s = lo;
    hi = n;
    while (lo < hi) { int mid = (lo + hi) >> 1; if (pool[mid] < p + 1) lo = mid + 1; else hi = mid; }
    int e = lo;
    float sum = 0.f;
    for (int i = s; i < e; ++i) sum += bf2f(h16[(size_t)i * D + d]);
    int c = e - s;
    outx[(size_t)p * D + d] = sum / (float)(c > 0 ? c : 1);
    if (d == 0) {
        int bm = INT_MIN;
        for (int i = s; i < e; ++i) bm = max(bm, nbatch[i]);
        outb[p] = (float)bm;
    }
}

extern "C" void kernel_launch(void* const* d_in, const int* in_sizes, int n_in,
                              void* d_out, int out_size, void* d_ws, size_t ws_size,
                              hipStream_t stream)
{
    const int*   x      = (const int*)d_in[0];
    const int*   ei     = (const int*)d_in[1];
    const int*   pool   = (const int*)d_in[2];
    const int*   nbatch = (const int*)d_in[3];
    const float* embed  = (const float*)d_in[5];
    const float* Wl     = (const float*)d_in[6];
    const float* Wr     = (const float*)d_in[7];
    const float* bias   = (const float*)d_in[8];

    const int N  = in_sizes[2];
    const int L  = in_sizes[0] / N;
    const int E  = in_sizes[1] / 2;
    const int VD = in_sizes[5];
    const int NL = in_sizes[6] / (D * D);
    const int P  = 5000;

    float* out_x   = (float*)d_out;
    float* out_adj = out_x + (size_t)P * D;
    float* out_b   = out_adj + (size_t)P * P;

    char* w = (char*)d_ws;
    auto alloc = [&](size_t bytes) { void* p = w; w += (bytes + 255) & ~255ULL; return p; };
    size_t ND = (size_t)N * D;
    unsigned short* h16   = (unsigned short*)alloc(ND * 2);
    unsigned short* agg16 = (unsigned short*)alloc(ND * 2);
    unsigned short* Wp    = (unsigned short*)alloc((size_t)NL * 2 * 16384 * 2);
    unsigned short* e16   = (unsigned short*)alloc((size_t)VD * 2);
    int*   col    = (int*)alloc((size_t)E * 4);
    int*   kbuf   = (int*)alloc((size_t)E * 4);
    int*   rpall  = (int*)alloc((size_t)(N + NBK + 1) * 4);
    int*   bsum   = (int*)alloc(256 * 4);
    int*   boff   = (int*)alloc(256 * 4);
    // zeroed region: degall(N+NBK) | cur(N) | bcur(NBK)
    int*   degall = (int*)alloc((size_t)(N + NBK + N + NBK) * 4);
    int*   cur    = degall + N + NBK;
    int*   bcur   = cur + N;

    const int NS = N + NBK;                    // scanned length
    const int NB = (NS + 1023) / 1024;         // scan blocks (<=256)

    size_t nz = ((size_t)(N + NBK) * 2 + 3) / 4;
    zero_k<<<(int)((nz + 255) / 256), 256, 0, stream>>>((float4*)degall, nz);

    epack_k<<<(VD / 4 + 255) / 256, 256, 0, stream>>>(embed, e16, VD / 4);
    wpack_k<<<(NL * 2 * 16384 + 255) / 256, 256, 0, stream>>>(Wl, Wr, Wp, NL);
    embed_pool_k<<<(N + 15) / 16, 256, 0, stream>>>(x, e16, h16, N, L);
    deghist_k<<<(E + 8191) / 8192, 256, 0, stream>>>(ei, pool, degall, E, N, P);
    scan_partial_k<<<NB, 256, 0, stream>>>(degall, bsum, NS);
    scan_bsum_k<<<1, 256, 0, stream>>>(bsum, boff, NB);
    scan_final_k<<<NB, 256, 0, stream>>>(degall, boff, rpall, NS);
    edge_pass2_k<<<(E + 255) / 256, 256, 0, stream>>>(
        ei, rpall, pool, cur, bcur, col, kbuf, E, N, P);
    adj_write_k<<<NBK, 256, 0, stream>>>(rpall, kbuf, out_adj, E, N);

    for (int ly = 0; ly < NL; ++ly) {
        aggregate_k<<<(N + 3) / 4, 256, 0, stream>>>(h16, rpall, col, agg16, N);
        sage_gemm_mfma_k<<<(N + 127) / 128, 256, 0, stream>>>(
            agg16, h16, Wp + (size_t)ly * 2 * 16384, bias + (size_t)ly * D, N);
    }

    poolmean_k<<<P, 128, 0, stream>>>(h16, pool, nbatch, out_x, out_b, N, P);
}

// Round 7
// 323.665 us; speedup vs baseline: 1.4798x; 1.4798x over previous
//
#include <hip/hip_runtime.h>
#include <limits.h>

#define D 128
#define NBK 768          // adjacency buckets: key>>15 (128KB adj window each)
#define EB  8192         // edges per histogram/scatter block

typedef __attribute__((ext_vector_type(8))) short bf16x8;
typedef __attribute__((ext_vector_type(4))) float f32x4;

static __device__ __forceinline__ unsigned short f2bf(float f) {
    unsigned u = __builtin_bit_cast(unsigned, f);
    u += 0x7FFFu + ((u >> 16) & 1u);            // RNE
    return (unsigned short)(u >> 16);
}
static __device__ __forceinline__ float bf2f(unsigned u16) {
    unsigned u = u16 << 16;
    return __builtin_bit_cast(float, u);
}
static __device__ __forceinline__ bf16x8 load_frag(const unsigned short* p) {
    uint4 v = *(const uint4*)p;
    return __builtin_bit_cast(bf16x8, v);
}
static __device__ __forceinline__ void acc8(float* a, uint4 v) {
    a[0] += bf2f(v.x & 0xffff); a[1] += bf2f(v.x >> 16);
    a[2] += bf2f(v.y & 0xffff); a[3] += bf2f(v.y >> 16);
    a[4] += bf2f(v.z & 0xffff); a[5] += bf2f(v.z >> 16);
    a[6] += bf2f(v.w & 0xffff); a[7] += bf2f(v.w >> 16);
}
static __device__ __forceinline__ ushort4 pack4(const float* a, float s) {
    ushort4 o;
    o.x = f2bf(a[0] * s); o.y = f2bf(a[1] * s);
    o.z = f2bf(a[2] * s); o.w = f2bf(a[3] * s);
    return o;
}

// ---------------- zero-fill scratch counters ----------------
__global__ __launch_bounds__(256) void zero_k(float4* __restrict__ b, size_t nb)
{
    size_t i = (size_t)blockIdx.x * 256 + threadIdx.x;
    if (i < nb) b[i] = make_float4(0.f, 0.f, 0.f, 0.f);
}

// ---------------- embed table -> bf16 ----------------
__global__ __launch_bounds__(256) void epack_k(
    const float* __restrict__ embed, unsigned short* __restrict__ e16, int n4)
{
    int i = blockIdx.x * 256 + threadIdx.x;
    if (i >= n4) return;
    float4 v = *(const float4*)&embed[(size_t)i * 4];
    ushort4 o;
    o.x = f2bf(v.x); o.y = f2bf(v.y); o.z = f2bf(v.z); o.w = f2bf(v.w);
    *(ushort4*)&e16[(size_t)i * 4] = o;
}

// ---------------- embedding masked mean-pool: 16 nodes/block, 16 lanes x 16B ----------------
__global__ __launch_bounds__(256) void embed_pool_k(
    const int* __restrict__ x, const unsigned short* __restrict__ e16,
    unsigned short* __restrict__ h16, int n, int L)
{
    __shared__ int toks[16][32];   // L <= 32
    int t = threadIdx.x;
    int sub = t >> 4, s = t & 15;
    int node = blockIdx.x * 16 + sub;
    for (int j = t; j < 16 * L; j += 256) {
        int nd = blockIdx.x * 16 + j / L;
        toks[j / L][j % L] = (nd < n) ? x[(size_t)nd * L + (j % L)] : 0;
    }
    __syncthreads();
    if (node >= n) return;
    float acc[8] = {};
    int cnt = 0;
    for (int l = 0; l < L; ++l) {
        int tok = toks[sub][l];
        if (tok != 0) {
            acc8(acc, *(const uint4*)&e16[(size_t)tok * D + s * 8]);
            cnt++;
        }
    }
    float inv = 1.0f / (float)(cnt > 0 ? cnt : 1);
    ushort4 lo = pack4(acc, inv), hi = pack4(acc + 4, inv);
    *(ushort4*)&h16[(size_t)node * D + s * 8]     = lo;
    *(ushort4*)&h16[(size_t)node * D + s * 8 + 4] = hi;
}

// ---------------- pack W into MFMA B-fragment order (bf16) ----------------
__global__ __launch_bounds__(256) void wpack_k(
    const float* __restrict__ Wl, const float* __restrict__ Wr,
    unsigned short* __restrict__ Wp, int NL)
{
    int idx = blockIdx.x * 256 + threadIdx.x;
    if (idx >= NL * 2 * 16384) return;
    int m = idx >> 14;
    int r = idx & 16383;
    int j = r & 7;
    int lane = (r >> 3) & 63;
    int cb = (r >> 9) & 7;
    int kb = (r >> 12) & 3;
    const float* W = ((m & 1) ? Wr : Wl) + (size_t)(m >> 1) * D * D;
    int k = kb * 32 + (lane >> 4) * 8 + j;
    int c = cb * 16 + (lane & 15);
    Wp[idx] = f2bf(W[(size_t)k * D + c]);
}

// ---------------- degree count + PER-BLOCK bucket histogram (no global hist atomics) ----------------
// degall = [deg(N) | bcnt[NBK][nblk]] ; block blk writes column blk of bcnt.
__global__ __launch_bounds__(256) void deghist_k(
    const int* __restrict__ ei, const int* __restrict__ pool,
    int* __restrict__ degall, int E, int n, int P, int nblk)
{
    __shared__ int hist[NBK];
    int t = threadIdx.x;
    for (int i = t; i < NBK; i += 256) hist[i] = 0;
    __syncthreads();
    int base = blockIdx.x * EB;
    int lim = min(E, base + EB);
    for (int e = base + t; e < lim; e += 256) {
        int src = ei[e], dst = ei[E + e];
        atomicAdd(&degall[dst], 1);
        int sp = pool[src], dp = pool[dst];
        if (sp != dp) atomicAdd(&hist[(sp * P + dp) >> 15], 1);
    }
    __syncthreads();
    for (int i = t; i < NBK; i += 256)
        degall[n + i * nblk + blockIdx.x] = hist[i];
}

// ---------------- hierarchical exclusive scan of degall -> rpall ----------------
__global__ __launch_bounds__(256) void scan_partial_k(
    const int* __restrict__ deg, int* __restrict__ bsum, int n)
{
    int b = blockIdx.x, t = threadIdx.x;
    int i0 = b * 1024 + t * 4;
    int s = 0;
    #pragma unroll
    for (int k = 0; k < 4; ++k) { int i = i0 + k; if (i < n) s += deg[i]; }
    for (int off = 32; off > 0; off >>= 1) s += __shfl_down(s, off, 64);
    __shared__ int sm4[4];
    if ((t & 63) == 0) sm4[t >> 6] = s;
    __syncthreads();
    if (t == 0) bsum[b] = sm4[0] + sm4[1] + sm4[2] + sm4[3];
}

__global__ __launch_bounds__(256) void scan_bsum_k(
    const int* __restrict__ bsum, int* __restrict__ boff, int nb)
{
    __shared__ int sm[256];
    int t = threadIdx.x;
    sm[t] = (t < nb) ? bsum[t] : 0;
    __syncthreads();
    for (int off = 1; off < 256; off <<= 1) {
        int add = (t >= off) ? sm[t - off] : 0;
        __syncthreads();
        sm[t] += add;
        __syncthreads();
    }
    if (t < nb) boff[t] = (t > 0) ? sm[t - 1] : 0;
}

__global__ __launch_bounds__(256) void scan_final_k(
    const int* __restrict__ deg, const int* __restrict__ boff,
    int* __restrict__ rp, int n)
{
    __shared__ int sm[256];
    int b = blockIdx.x, t = threadIdx.x;
    int i0 = b * 1024 + t * 4;
    int v[4];
    #pragma unroll
    for (int k = 0; k < 4; ++k) { int i = i0 + k; v[k] = (i < n) ? deg[i] : 0; }
    v[1] += v[0]; v[2] += v[1]; v[3] += v[2];
    sm[t] = v[3];
    __syncthreads();
    for (int off = 1; off < 256; off <<= 1) {
        int add = (t >= off) ? sm[t - off] : 0;
        __syncthreads();
        sm[t] += add;
        __syncthreads();
    }
    int base = boff[b] + ((t > 0) ? sm[t - 1] : 0);
    if (b == 0 && t == 0) rp[0] = 0;
    #pragma unroll
    for (int k = 0; k < 4; ++k) {
        int i = i0 + k;
        if (i < n) rp[i + 1] = base + v[k];
    }
}

// ---------------- scatter: CSR + bucket keys, LDS-allocated positions ----------------
__global__ __launch_bounds__(256) void edge_scatter_k(
    const int* __restrict__ ei, const int* __restrict__ rpall,
    const int* __restrict__ pool, int* __restrict__ cur,
    int* __restrict__ col, int* __restrict__ kbuf, int E, int n, int P, int nblk)
{
    __shared__ int off[NBK];
    int t = threadIdx.x;
    for (int i = t; i < NBK; i += 256)
        off[i] = rpall[n + i * nblk + blockIdx.x] - E;   // this block's base per bucket
    __syncthreads();
    int base = blockIdx.x * EB;
    int lim = min(E, base + EB);
    for (int e = base + t; e < lim; e += 256) {
        int src = ei[e], dst = ei[E + e];
        int pos = atomicAdd(&cur[dst], 1);
        col[rpall[dst] + pos] = src;
        int sp = pool[src], dp = pool[dst];
        if (sp != dp) {
            int key = sp * P + dp;
            int kpos = atomicAdd(&off[key >> 15], 1);    // LDS atomic
            kbuf[kpos] = key;
        }
    }
}

// ---------------- adjacency write: one block per bucket (128KB adj window) ----------------
__global__ __launch_bounds__(256) void adj_write_k(
    const int* __restrict__ rpall, const int* __restrict__ kbuf,
    float* __restrict__ adj, int E, int n, int nblk, int ns)
{
    int b = blockIdx.x;
    int s = rpall[n + b * nblk] - E;
    int e = (b == NBK - 1) ? (rpall[ns] - E) : (rpall[n + (b + 1) * nblk] - E);
    for (int i = s + threadIdx.x; i < e; i += 256)
        adj[(size_t)kbuf[i]] = 1.0f;
}

// ---------------- neighbor mean-aggregate: quarter-wave per edge, 8 edges in flight ----------------
__global__ __launch_bounds__(256) void aggregate_k(
    const unsigned short* __restrict__ h16, const int* __restrict__ rp,
    const int* __restrict__ col, unsigned short* __restrict__ agg16, int n)
{
    int node = blockIdx.x * 4 + (threadIdx.x >> 6);
    int lane = threadIdx.x & 63;
    if (node >= n) return;
    int beg = rp[node], end = rp[node + 1];
    int q = lane >> 4, s = lane & 15;
    float acc[8] = {};
    int e = beg + q;
    for (; e + 4 < end; e += 8) {
        int s0 = col[e], s1 = col[e + 4];
        uint4 v0 = *(const uint4*)&h16[(size_t)s0 * D + s * 8];
        uint4 v1 = *(const uint4*)&h16[(size_t)s1 * D + s * 8];
        acc8(acc, v0);
        acc8(acc, v1);
    }
    if (e < end)
        acc8(acc, *(const uint4*)&h16[(size_t)col[e] * D + s * 8]);
    #pragma unroll
    for (int k = 0; k < 8; ++k) {
        acc[k] += __shfl_xor(acc[k], 16, 64);
        acc[k] += __shfl_xor(acc[k], 32, 64);
    }
    if (q == 0) {
        int dg = end - beg;
        float inv = 1.0f / (float)(dg > 0 ? dg : 1);
        ushort4 lo = pack4(acc, inv), hi = pack4(acc + 4, inv);
        *(ushort4*)&agg16[(size_t)node * D + s * 8]     = lo;
        *(ushort4*)&agg16[(size_t)node * D + s * 8 + 4] = hi;
    }
}

// ---------------- SAGE layer GEMM via MFMA (in-place safe) ----------------
__global__ __launch_bounds__(256) void sage_gemm_mfma_k(
    const unsigned short* __restrict__ agg16, unsigned short* __restrict__ h16,
    const unsigned short* __restrict__ Wp,   // [2][4][8][64][8]
    const float* __restrict__ bias, int n)
{
    int t = threadIdx.x;
    int w = t >> 6, lane = t & 63;
    int node0 = blockIdx.x * 128 + w * 32;
    int row = lane & 15, g = lane >> 4;

    f32x4 acc[2][8];
    #pragma unroll
    for (int i = 0; i < 2; ++i)
        #pragma unroll
        for (int c = 0; c < 8; ++c)
            acc[i][c] = (f32x4){0.f, 0.f, 0.f, 0.f};

    float bs[8];
    #pragma unroll
    for (int cb = 0; cb < 8; ++cb) bs[cb] = bias[cb * 16 + row];

    bool ok0 = (node0 < n);
    bool ok1 = (node0 + 16 < n);

    #pragma unroll
    for (int kb = 0; kb < 8; ++kb) {
        const unsigned short* Asrc = (kb < 4) ? agg16 : h16;
        int ko = (kb & 3) * 32 + g * 8;
        bf16x8 a0 = (bf16x8){0,0,0,0,0,0,0,0};
        bf16x8 a1 = a0;
        if (ok0) a0 = load_frag(&Asrc[(size_t)(node0 + row) * D + ko]);
        if (ok1) a1 = load_frag(&Asrc[(size_t)(node0 + 16 + row) * D + ko]);
        const unsigned short* wp = Wp + ((kb < 4) ? 0 : 16384) + (size_t)(kb & 3) * 4096;
        #pragma unroll
        for (int cb = 0; cb < 8; ++cb) {
            bf16x8 b = load_frag(&wp[(cb * 64 + lane) * 8]);
            acc[0][cb] = __builtin_amdgcn_mfma_f32_16x16x32_bf16(a0, b, acc[0][cb], 0, 0, 0);
            acc[1][cb] = __builtin_amdgcn_mfma_f32_16x16x32_bf16(a1, b, acc[1][cb], 0, 0, 0);
        }
    }

    #pragma unroll
    for (int rg = 0; rg < 2; ++rg) {
        int nb = node0 + rg * 16;
        if (nb >= n) break;
        #pragma unroll
        for (int cb = 0; cb < 8; ++cb) {
            int c = cb * 16 + row;
            #pragma unroll
            for (int j = 0; j < 4; ++j) {
                int node = nb + g * 4 + j;
                float v = fmaxf(acc[rg][cb][j] + bs[cb], 0.f);
                h16[(size_t)node * D + c] = f2bf(v);
            }
        }
    }
}

// ---------------- pooled mean + batch max (pool_idx sorted/grouped; no atomics) ----------------
__global__ __launch_bounds__(128) void poolmean_k(
    const unsigned short* __restrict__ h16, const int* __restrict__ pool,
    const int* __restrict__ nbatch, float* __restrict__ outx,
    float* __restrict__ outb, int n, int P)
{
    int p = blockIdx.x;
    int d = threadIdx.x;
    int lo = 0, hi = n;
    while (lo < hi) { int mid = (lo + hi) >> 1; if (pool[mid] < p) lo = mid + 1; else hi = mid; }
    int s = lo;
    hi = n;
    while (lo < hi) { int mid = (lo + hi) >> 1; if (pool[mid] < p + 1) lo = mid + 1; else hi = mid; }
    int e = lo;
    float sum = 0.f;
    for (int i = s; i < e; ++i) sum += bf2f(h16[(size_t)i * D + d]);
    int c = e - s;
    outx[(size_t)p * D + d] = sum / (float)(c > 0 ? c : 1);
    if (d == 0) {
        int bm = INT_MIN;
        for (int i = s; i < e; ++i) bm = max(bm, nbatch[i]);
        outb[p] = (float)bm;
    }
}

extern "C" void kernel_launch(void* const* d_in, const int* in_sizes, int n_in,
                              void* d_out, int out_size, void* d_ws, size_t ws_size,
                              hipStream_t stream)
{
    const int*   x      = (const int*)d_in[0];
    const int*   ei     = (const int*)d_in[1];
    const int*   pool   = (const int*)d_in[2];
    const int*   nbatch = (const int*)d_in[3];
    const float* embed  = (const float*)d_in[5];
    const float* Wl     = (const float*)d_in[6];
    const float* Wr     = (const float*)d_in[7];
    const float* bias   = (const float*)d_in[8];

    const int N  = in_sizes[2];
    const int L  = in_sizes[0] / N;
    const int E  = in_sizes[1] / 2;
    const int VD = in_sizes[5];
    const int NL = in_sizes[6] / (D * D);
    const int P  = 5000;

    float* out_x   = (float*)d_out;
    float* out_adj = out_x + (size_t)P * D;
    float* out_b   = out_adj + (size_t)P * P;

    char* w = (char*)d_ws;
    auto alloc = [&](size_t bytes) { void* p = w; w += (bytes + 255) & ~255ULL; return p; };
    size_t ND = (size_t)N * D;
    unsigned short* h16   = (unsigned short*)alloc(ND * 2);
    unsigned short* agg16 = (unsigned short*)alloc(ND * 2);
    unsigned short* Wp    = (unsigned short*)alloc((size_t)NL * 2 * 16384 * 2);
    unsigned short* e16   = (unsigned short*)alloc((size_t)VD * 2);

    const int NBLK = (E + EB - 1) / EB;        // scatter blocks (98)
    const int NS   = N + NBK * NBLK;           // scanned length (125264)
    const int NB   = (NS + 1023) / 1024;       // scan blocks (<=256)

    int*   col    = (int*)alloc((size_t)E * 4);
    int*   kbuf   = (int*)alloc((size_t)E * 4);
    int*   rpall  = (int*)alloc((size_t)(NS + 1) * 4);
    int*   bsum   = (int*)alloc(256 * 4);
    int*   boff   = (int*)alloc(256 * 4);
    // zeroed region: degall(NS) | cur(N)
    int*   degall = (int*)alloc((size_t)(NS + N) * 4);
    int*   cur    = degall + NS;

    size_t nz = ((size_t)(NS + N) + 3) / 4;
    zero_k<<<(int)((nz + 255) / 256), 256, 0, stream>>>((float4*)degall, nz);

    epack_k<<<(VD / 4 + 255) / 256, 256, 0, stream>>>(embed, e16, VD / 4);
    wpack_k<<<(NL * 2 * 16384 + 255) / 256, 256, 0, stream>>>(Wl, Wr, Wp, NL);
    embed_pool_k<<<(N + 15) / 16, 256, 0, stream>>>(x, e16, h16, N, L);
    deghist_k<<<NBLK, 256, 0, stream>>>(ei, pool, degall, E, N, P, NBLK);
    scan_partial_k<<<NB, 256, 0, stream>>>(degall, bsum, NS);
    scan_bsum_k<<<1, 256, 0, stream>>>(bsum, boff, NB);
    scan_final_k<<<NB, 256, 0, stream>>>(degall, boff, rpall, NS);
    edge_scatter_k<<<NBLK, 256, 0, stream>>>(ei, rpall, pool, cur, col, kbuf, E, N, P, NBLK);
    adj_write_k<<<NBK, 256, 0, stream>>>(rpall, kbuf, out_adj, E, N, NBLK, NS);

    for (int ly = 0; ly < NL; ++ly) {
        aggregate_k<<<(N + 3) / 4, 256, 0, stream>>>(h16, rpall, col, agg16, N);
        sage_gemm_mfma_k<<<(N + 127) / 128, 256, 0, stream>>>(
            agg16, h16, Wp + (size_t)ly * 2 * 16384, bias + (size_t)ly * D, N);
    }

    poolmean_k<<<P, 128, 0, stream>>>(h16, pool, nbatch, out_x, out_b, N, P);
}

// Round 8
// 308.415 us; speedup vs baseline: 1.5530x; 1.0494x over previous
//
#include <hip/hip_runtime.h>
#include <limits.h>

#define D 128
#define NBK 768          // adjacency buckets: key>>15 (128KB adj window each)
#define EB  2048         // edges per histogram/bucket-scatter block

typedef __attribute__((ext_vector_type(8))) short bf16x8;
typedef __attribute__((ext_vector_type(4))) float f32x4;

static __device__ __forceinline__ unsigned short f2bf(float f) {
    unsigned u = __builtin_bit_cast(unsigned, f);
    u += 0x7FFFu + ((u >> 16) & 1u);            // RNE
    return (unsigned short)(u >> 16);
}
static __device__ __forceinline__ float bf2f(unsigned u16) {
    unsigned u = u16 << 16;
    return __builtin_bit_cast(float, u);
}
static __device__ __forceinline__ bf16x8 load_frag(const unsigned short* p) {
    uint4 v = *(const uint4*)p;
    return __builtin_bit_cast(bf16x8, v);
}
static __device__ __forceinline__ void acc8(float* a, uint4 v) {
    a[0] += bf2f(v.x & 0xffff); a[1] += bf2f(v.x >> 16);
    a[2] += bf2f(v.y & 0xffff); a[3] += bf2f(v.y >> 16);
    a[4] += bf2f(v.z & 0xffff); a[5] += bf2f(v.z >> 16);
    a[6] += bf2f(v.w & 0xffff); a[7] += bf2f(v.w >> 16);
}
static __device__ __forceinline__ ushort4 pack4(const float* a, float s) {
    ushort4 o;
    o.x = f2bf(a[0] * s); o.y = f2bf(a[1] * s);
    o.z = f2bf(a[2] * s); o.w = f2bf(a[3] * s);
    return o;
}

// ---------------- zero-fill scratch counters ----------------
__global__ __launch_bounds__(256) void zero_k(float4* __restrict__ b, size_t nb)
{
    size_t i = (size_t)blockIdx.x * 256 + threadIdx.x;
    if (i < nb) b[i] = make_float4(0.f, 0.f, 0.f, 0.f);
}

// ---------------- embed table -> bf16 ----------------
__global__ __launch_bounds__(256) void epack_k(
    const float* __restrict__ embed, unsigned short* __restrict__ e16, int n4)
{
    int i = blockIdx.x * 256 + threadIdx.x;
    if (i >= n4) return;
    float4 v = *(const float4*)&embed[(size_t)i * 4];
    ushort4 o;
    o.x = f2bf(v.x); o.y = f2bf(v.y); o.z = f2bf(v.z); o.w = f2bf(v.w);
    *(ushort4*)&e16[(size_t)i * 4] = o;
}

// ---------------- embedding masked mean-pool: 16 nodes/block, 16 lanes x 16B ----------------
__global__ __launch_bounds__(256) void embed_pool_k(
    const int* __restrict__ x, const unsigned short* __restrict__ e16,
    unsigned short* __restrict__ h16, int n, int L)
{
    __shared__ int toks[16][32];   // L <= 32
    int t = threadIdx.x;
    int sub = t >> 4, s = t & 15;
    int node = blockIdx.x * 16 + sub;
    for (int j = t; j < 16 * L; j += 256) {
        int nd = blockIdx.x * 16 + j / L;
        toks[j / L][j % L] = (nd < n) ? x[(size_t)nd * L + (j % L)] : 0;
    }
    __syncthreads();
    if (node >= n) return;
    float acc[8] = {};
    int cnt = 0;
    for (int l = 0; l < L; ++l) {
        int tok = toks[sub][l];
        if (tok != 0) {
            acc8(acc, *(const uint4*)&e16[(size_t)tok * D + s * 8]);
            cnt++;
        }
    }
    float inv = 1.0f / (float)(cnt > 0 ? cnt : 1);
    ushort4 lo = pack4(acc, inv), hi = pack4(acc + 4, inv);
    *(ushort4*)&h16[(size_t)node * D + s * 8]     = lo;
    *(ushort4*)&h16[(size_t)node * D + s * 8 + 4] = hi;
}

// ---------------- pack W into MFMA B-fragment order (bf16) ----------------
__global__ __launch_bounds__(256) void wpack_k(
    const float* __restrict__ Wl, const float* __restrict__ Wr,
    unsigned short* __restrict__ Wp, int NL)
{
    int idx = blockIdx.x * 256 + threadIdx.x;
    if (idx >= NL * 2 * 16384) return;
    int m = idx >> 14;
    int r = idx & 16383;
    int j = r & 7;
    int lane = (r >> 3) & 63;
    int cb = (r >> 9) & 7;
    int kb = (r >> 12) & 3;
    const float* W = ((m & 1) ? Wr : Wl) + (size_t)(m >> 1) * D * D;
    int k = kb * 32 + (lane >> 4) * 8 + j;
    int c = cb * 16 + (lane & 15);
    Wp[idx] = f2bf(W[(size_t)k * D + c]);
}

// ---------------- degree count + PER-BLOCK bucket histogram ----------------
// degall = [deg(N) | bcnt[NBK][nblk]] ; block blk writes column blk of bcnt.
__global__ __launch_bounds__(256) void deghist_k(
    const int* __restrict__ ei, const int* __restrict__ pool,
    int* __restrict__ degall, int E, int n, int P, int nblk)
{
    __shared__ int hist[NBK];
    int t = threadIdx.x;
    for (int i = t; i < NBK; i += 256) hist[i] = 0;
    __syncthreads();
    int base = blockIdx.x * EB;
    int lim = min(E, base + EB);
    for (int e = base + t; e < lim; e += 256) {
        int src = ei[e], dst = ei[E + e];
        atomicAdd(&degall[dst], 1);
        int sp = pool[src], dp = pool[dst];
        if (sp != dp) atomicAdd(&hist[(sp * P + dp) >> 15], 1);
    }
    __syncthreads();
    for (int i = t; i < NBK; i += 256)
        degall[n + i * nblk + blockIdx.x] = hist[i];
}

// ---------------- hierarchical exclusive scan of degall -> rpall ----------------
__global__ __launch_bounds__(256) void scan_partial_k(
    const int* __restrict__ deg, int* __restrict__ bsum, int n)
{
    int b = blockIdx.x, t = threadIdx.x;
    int i0 = b * 1024 + t * 4;
    int s = 0;
    #pragma unroll
    for (int k = 0; k < 4; ++k) { int i = i0 + k; if (i < n) s += deg[i]; }
    for (int off = 32; off > 0; off >>= 1) s += __shfl_down(s, off, 64);
    __shared__ int sm4[4];
    if ((t & 63) == 0) sm4[t >> 6] = s;
    __syncthreads();
    if (t == 0) bsum[b] = sm4[0] + sm4[1] + sm4[2] + sm4[3];
}

// 512 threads: supports up to 512 scan blocks (524288 scanned elements)
__global__ __launch_bounds__(512) void scan_bsum_k(
    const int* __restrict__ bsum, int* __restrict__ boff, int nb)
{
    __shared__ int sm[512];
    int t = threadIdx.x;
    sm[t] = (t < nb) ? bsum[t] : 0;
    __syncthreads();
    for (int off = 1; off < 512; off <<= 1) {
        int add = (t >= off) ? sm[t - off] : 0;
        __syncthreads();
        sm[t] += add;
        __syncthreads();
    }
    if (t < nb) boff[t] = (t > 0) ? sm[t - 1] : 0;
}

__global__ __launch_bounds__(256) void scan_final_k(
    const int* __restrict__ deg, const int* __restrict__ boff,
    int* __restrict__ rp, int n)
{
    __shared__ int sm[256];
    int b = blockIdx.x, t = threadIdx.x;
    int i0 = b * 1024 + t * 4;
    int v[4];
    #pragma unroll
    for (int k = 0; k < 4; ++k) { int i = i0 + k; v[k] = (i < n) ? deg[i] : 0; }
    v[1] += v[0]; v[2] += v[1]; v[3] += v[2];
    sm[t] = v[3];
    __syncthreads();
    for (int off = 1; off < 256; off <<= 1) {
        int add = (t >= off) ? sm[t - off] : 0;
        __syncthreads();
        sm[t] += add;
        __syncthreads();
    }
    int base = boff[b] + ((t > 0) ? sm[t - 1] : 0);
    if (b == 0 && t == 0) rp[0] = 0;
    #pragma unroll
    for (int k = 0; k < 4; ++k) {
        int i = i0 + k;
        if (i < n) rp[i + 1] = base + v[k];
    }
}

// ---------------- CSR scatter: max-parallelism, one edge per thread ----------------
__global__ __launch_bounds__(256) void csr_scatter_k(
    const int* __restrict__ ei, const int* __restrict__ rpall,
    int* __restrict__ cur, int* __restrict__ col, int E)
{
    int e = blockIdx.x * 256 + threadIdx.x;
    if (e >= E) return;
    int src = ei[e], dst = ei[E + e];
    int pos = atomicAdd(&cur[dst], 1);
    col[rpall[dst] + pos] = src;
}

// ---------------- bucket-key scatter: LDS-allocated positions ----------------
__global__ __launch_bounds__(256) void bkt_scatter_k(
    const int* __restrict__ ei, const int* __restrict__ rpall,
    const int* __restrict__ pool, int* __restrict__ kbuf,
    int E, int n, int P, int nblk)
{
    __shared__ int off[NBK];
    int t = threadIdx.x;
    for (int i = t; i < NBK; i += 256)
        off[i] = rpall[n + i * nblk + blockIdx.x] - E;   // this block's base per bucket
    __syncthreads();
    int base = blockIdx.x * EB;
    int lim = min(E, base + EB);
    for (int e = base + t; e < lim; e += 256) {
        int src = ei[e], dst = ei[E + e];
        int sp = pool[src], dp = pool[dst];
        if (sp != dp) {
            int key = sp * P + dp;
            int kpos = atomicAdd(&off[key >> 15], 1);    // LDS atomic
            kbuf[kpos] = key;
        }
    }
}

// ---------------- adjacency write: one block per bucket (128KB adj window) ----------------
__global__ __launch_bounds__(256) void adj_write_k(
    const int* __restrict__ rpall, const int* __restrict__ kbuf,
    float* __restrict__ adj, int E, int n, int nblk, int ns)
{
    int b = blockIdx.x;
    int s = rpall[n + b * nblk] - E;
    int e = (b == NBK - 1) ? (rpall[ns] - E) : (rpall[n + (b + 1) * nblk] - E);
    for (int i = s + threadIdx.x; i < e; i += 256)
        adj[(size_t)kbuf[i]] = 1.0f;
}

// ---------------- neighbor mean-aggregate: quarter-wave per edge, 8 edges in flight ----------------
__global__ __launch_bounds__(256) void aggregate_k(
    const unsigned short* __restrict__ h16, const int* __restrict__ rp,
    const int* __restrict__ col, unsigned short* __restrict__ agg16, int n)
{
    int node = blockIdx.x * 4 + (threadIdx.x >> 6);
    int lane = threadIdx.x & 63;
    if (node >= n) return;
    int beg = rp[node], end = rp[node + 1];
    int q = lane >> 4, s = lane & 15;
    float acc[8] = {};
    int e = beg + q;
    for (; e + 4 < end; e += 8) {
        int s0 = col[e], s1 = col[e + 4];
        uint4 v0 = *(const uint4*)&h16[(size_t)s0 * D + s * 8];
        uint4 v1 = *(const uint4*)&h16[(size_t)s1 * D + s * 8];
        acc8(acc, v0);
        acc8(acc, v1);
    }
    if (e < end)
        acc8(acc, *(const uint4*)&h16[(size_t)col[e] * D + s * 8]);
    #pragma unroll
    for (int k = 0; k < 8; ++k) {
        acc[k] += __shfl_xor(acc[k], 16, 64);
        acc[k] += __shfl_xor(acc[k], 32, 64);
    }
    if (q == 0) {
        int dg = end - beg;
        float inv = 1.0f / (float)(dg > 0 ? dg : 1);
        ushort4 lo = pack4(acc, inv), hi = pack4(acc + 4, inv);
        *(ushort4*)&agg16[(size_t)node * D + s * 8]     = lo;
        *(ushort4*)&agg16[(size_t)node * D + s * 8 + 4] = hi;
    }
}

// ---------------- SAGE layer GEMM via MFMA (in-place safe) ----------------
__global__ __launch_bounds__(256) void sage_gemm_mfma_k(
    const unsigned short* __restrict__ agg16, unsigned short* __restrict__ h16,
    const unsigned short* __restrict__ Wp,   // [2][4][8][64][8]
    const float* __restrict__ bias, int n)
{
    int t = threadIdx.x;
    int w = t >> 6, lane = t & 63;
    int node0 = blockIdx.x * 128 + w * 32;
    int row = lane & 15, g = lane >> 4;

    f32x4 acc[2][8];
    #pragma unroll
    for (int i = 0; i < 2; ++i)
        #pragma unroll
        for (int c = 0; c < 8; ++c)
            acc[i][c] = (f32x4){0.f, 0.f, 0.f, 0.f};

    float bs[8];
    #pragma unroll
    for (int cb = 0; cb < 8; ++cb) bs[cb] = bias[cb * 16 + row];

    bool ok0 = (node0 < n);
    bool ok1 = (node0 + 16 < n);

    #pragma unroll
    for (int kb = 0; kb < 8; ++kb) {
        const unsigned short* Asrc = (kb < 4) ? agg16 : h16;
        int ko = (kb & 3) * 32 + g * 8;
        bf16x8 a0 = (bf16x8){0,0,0,0,0,0,0,0};
        bf16x8 a1 = a0;
        if (ok0) a0 = load_frag(&Asrc[(size_t)(node0 + row) * D + ko]);
        if (ok1) a1 = load_frag(&Asrc[(size_t)(node0 + 16 + row) * D + ko]);
        const unsigned short* wp = Wp + ((kb < 4) ? 0 : 16384) + (size_t)(kb & 3) * 4096;
        #pragma unroll
        for (int cb = 0; cb < 8; ++cb) {
            bf16x8 b = load_frag(&wp[(cb * 64 + lane) * 8]);
            acc[0][cb] = __builtin_amdgcn_mfma_f32_16x16x32_bf16(a0, b, acc[0][cb], 0, 0, 0);
            acc[1][cb] = __builtin_amdgcn_mfma_f32_16x16x32_bf16(a1, b, acc[1][cb], 0, 0, 0);
        }
    }

    #pragma unroll
    for (int rg = 0; rg < 2; ++rg) {
        int nb = node0 + rg * 16;
        if (nb >= n) break;
        #pragma unroll
        for (int cb = 0; cb < 8; ++cb) {
            int c = cb * 16 + row;
            #pragma unroll
            for (int j = 0; j < 4; ++j) {
                int node = nb + g * 4 + j;
                float v = fmaxf(acc[rg][cb][j] + bs[cb], 0.f);
                h16[(size_t)node * D + c] = f2bf(v);
            }
        }
    }
}

// ---------------- pooled mean + batch max (pool_idx sorted/grouped; no atomics) ----------------
__global__ __launch_bounds__(128) void poolmean_k(
    const unsigned short* __restrict__ h16, const int* __restrict__ pool,
    const int* __restrict__ nbatch, float* __restrict__ outx,
    float* __restrict__ outb, int n, int P)
{
    int p = blockIdx.x;
    int d = threadIdx.x;
    int lo = 0, hi = n;
    while (lo < hi) { int mid = (lo + hi) >> 1; if (pool[mid] < p) lo = mid + 1; else hi = mid; }
    int s = lo;
    hi = n;
    while (lo < hi) { int mid = (lo + hi) >> 1; if (pool[mid] < p + 1) lo = mid + 1; else hi = mid; }
    int e = lo;
    float sum = 0.f;
    for (int i = s; i < e; ++i) sum += bf2f(h16[(size_t)i * D + d]);
    int c = e - s;
    outx[(size_t)p * D + d] = sum / (float)(c > 0 ? c : 1);
    if (d == 0) {
        int bm = INT_MIN;
        for (int i = s; i < e; ++i) bm = max(bm, nbatch[i]);
        outb[p] = (float)bm;
    }
}

extern "C" void kernel_launch(void* const* d_in, const int* in_sizes, int n_in,
                              void* d_out, int out_size, void* d_ws, size_t ws_size,
                              hipStream_t stream)
{
    const int*   x      = (const int*)d_in[0];
    const int*   ei     = (const int*)d_in[1];
    const int*   pool   = (const int*)d_in[2];
    const int*   nbatch = (const int*)d_in[3];
    const float* embed  = (const float*)d_in[5];
    const float* Wl     = (const float*)d_in[6];
    const float* Wr     = (const float*)d_in[7];
    const float* bias   = (const float*)d_in[8];

    const int N  = in_sizes[2];
    const int L  = in_sizes[0] / N;
    const int E  = in_sizes[1] / 2;
    const int VD = in_sizes[5];
    const int NL = in_sizes[6] / (D * D);
    const int P  = 5000;

    float* out_x   = (float*)d_out;
    float* out_adj = out_x + (size_t)P * D;
    float* out_b   = out_adj + (size_t)P * P;

    char* w = (char*)d_ws;
    auto alloc = [&](size_t bytes) { void* p = w; w += (bytes + 255) & ~255ULL; return p; };
    size_t ND = (size_t)N * D;
    unsigned short* h16   = (unsigned short*)alloc(ND * 2);
    unsigned short* agg16 = (unsigned short*)alloc(ND * 2);
    unsigned short* Wp    = (unsigned short*)alloc((size_t)NL * 2 * 16384 * 2);
    unsigned short* e16   = (unsigned short*)alloc((size_t)VD * 2);

    const int NBLK = (E + EB - 1) / EB;        // bucket blocks (391)
    const int NS   = N + NBK * NBLK;           // scanned length (~350K)
    const int NB   = (NS + 1023) / 1024;       // scan blocks (<=512)

    int*   col    = (int*)alloc((size_t)E * 4);
    int*   kbuf   = (int*)alloc((size_t)E * 4);
    int*   rpall  = (int*)alloc((size_t)(NS + 1) * 4);
    int*   bsum   = (int*)alloc(512 * 4);
    int*   boff   = (int*)alloc(512 * 4);
    // zeroed region: degall(NS) | cur(N)
    int*   degall = (int*)alloc((size_t)(NS + N) * 4);
    int*   cur    = degall + NS;

    size_t nz = ((size_t)(NS + N) + 3) / 4;
    zero_k<<<(int)((nz + 255) / 256), 256, 0, stream>>>((float4*)degall, nz);

    epack_k<<<(VD / 4 + 255) / 256, 256, 0, stream>>>(embed, e16, VD / 4);
    wpack_k<<<(NL * 2 * 16384 + 255) / 256, 256, 0, stream>>>(Wl, Wr, Wp, NL);
    embed_pool_k<<<(N + 15) / 16, 256, 0, stream>>>(x, e16, h16, N, L);
    deghist_k<<<NBLK, 256, 0, stream>>>(ei, pool, degall, E, N, P, NBLK);
    scan_partial_k<<<NB, 256, 0, stream>>>(degall, bsum, NS);
    scan_bsum_k<<<1, 512, 0, stream>>>(bsum, boff, NB);
    scan_final_k<<<NB, 256, 0, stream>>>(degall, boff, rpall, NS);
    csr_scatter_k<<<(E + 255) / 256, 256, 0, stream>>>(ei, rpall, cur, col, E);
    bkt_scatter_k<<<NBLK, 256, 0, stream>>>(ei, rpall, pool, kbuf, E, N, P, NBLK);
    adj_write_k<<<NBK, 256, 0, stream>>>(rpall, kbuf, out_adj, E, N, NBLK, NS);

    for (int ly = 0; ly < NL; ++ly) {
        aggregate_k<<<(N + 3) / 4, 256, 0, stream>>>(h16, rpall, col, agg16, N);
        sage_gemm_mfma_k<<<(N + 127) / 128, 256, 0, stream>>>(
            agg16, h16, Wp + (size_t)ly * 2 * 16384, bias + (size_t)ly * D, N);
    }

    poolmean_k<<<P, 128, 0, stream>>>(h16, pool, nbatch, out_x, out_b, N, P);
}